// Round 2
// baseline (1319.576 us; speedup 1.0000x reference)
//
#include <hip/hip_runtime.h>
#include <math.h>

#define NND 50000
#define DEG 16

typedef __attribute__((ext_vector_type(8))) short short8v;
typedef __attribute__((ext_vector_type(4))) float float4v;

// ---- workspace layout (bytes) ----
#define OFF_HPRE 0ULL          // N x 64 f32
#define OFF_PROJ 12800000ULL   // N x 64 f32
#define OFF_XB   25600000ULL   // N x 128 bf16
#define OFF_HBA  38400000ULL   // N x 128 bf16
#define OFF_HBB  51200000ULL   // N x 128 bf16
#define OFF_IDX  64000000ULL   // 5*N int
#define OFF_CUR  65000192ULL   // N int
#define OFF_BQT  65200384ULL   // 512 x 256 bf16 (quad-packed [Wh;Wx], col-major-T)
#define OFF_WOT  65462528ULL   // 128 x 128 bf16 (Wo^T)
#define WS_NEED  65495296ULL

__device__ __forceinline__ float sigf(float x){ return 1.0f/(1.0f + expf(-x)); }
__device__ __forceinline__ unsigned short f2bf(float f){
    unsigned int u = __float_as_uint(f);
    u += 0x7FFFu + ((u >> 16) & 1u);
    return (unsigned short)(u >> 16);
}
__device__ __forceinline__ float bf2f(unsigned short h){
    return __uint_as_float(((unsigned int)h) << 16);
}

__global__ __launch_bounds__(256) void k_iota(int* __restrict__ cur, int* __restrict__ idx0){
    int i = blockIdx.x*256 + threadIdx.x;
    if (i < NND){ cur[i] = i; idx0[i] = i; }
}

// ---------------- walk phase (fp32, untouched: argmax determinism) ----------------
// out(N x 64) = A(N x 128) @ B(128 x 64) [+ bias]; BM=64 BN=64 KC=32
__global__ __launch_bounds__(256) void k_proj(const float* __restrict__ A,
    const float* __restrict__ B, const float* __restrict__ bias,
    float* __restrict__ out)
{
    __shared__ float Al[64][33];
    __shared__ float Bl[32][68];
    const int tid = threadIdx.x;
    const int row0 = blockIdx.x << 6;
    const int row_t = tid >> 4, col_t = tid & 15;
    float4 acc[4];
#pragma unroll
    for (int i=0;i<4;i++) acc[i] = make_float4(0.f,0.f,0.f,0.f);
    for (int k0 = 0; k0 < 128; k0 += 32){
#pragma unroll
        for (int r=0;r<2;r++){
            int am = (tid>>3) + (r<<5);
            int ak = (tid&7) << 2;
            int gr = row0 + am; if (gr >= NND) gr = NND-1;
            float4 v = *(const float4*)(A + (size_t)gr*128 + k0 + ak);
            Al[am][ak] = v.x; Al[am][ak+1] = v.y; Al[am][ak+2] = v.z; Al[am][ak+3] = v.w;
        }
#pragma unroll
        for (int r=0;r<2;r++){
            int p = (r<<8) + tid;
            int bk = p >> 4, bc = (p & 15) << 2;
            *(float4*)(&Bl[bk][bc]) = *(const float4*)(B + (size_t)(k0+bk)*64 + bc);
        }
        __syncthreads();
#pragma unroll 8
        for (int k=0;k<32;k++){
            float4 b = *(const float4*)(&Bl[k][col_t<<2]);
#pragma unroll
            for (int i=0;i<4;i++){
                float a = Al[(row_t<<2)+i][k];
                acc[i].x = fmaf(a, b.x, acc[i].x);
                acc[i].y = fmaf(a, b.y, acc[i].y);
                acc[i].z = fmaf(a, b.z, acc[i].z);
                acc[i].w = fmaf(a, b.w, acc[i].w);
            }
        }
        __syncthreads();
    }
    float4 bb = make_float4(0.f,0.f,0.f,0.f);
    if (bias) bb = *(const float4*)(bias + (col_t<<2));
#pragma unroll
    for (int i=0;i<4;i++){
        int gr = row0 + (row_t<<2) + i;
        if (gr < NND){
            float4 o = make_float4(acc[i].x+bb.x, acc[i].y+bb.y, acc[i].z+bb.z, acc[i].w+bb.w);
            *(float4*)(out + (size_t)gr*64 + (col_t<<2)) = o;
        }
    }
}

// one walk step: 16 nodes/block, thread <-> (node, d)
__global__ __launch_bounds__(256) void k_walk(float* __restrict__ hpre,
    const float* __restrict__ proj, const int* __restrict__ dst,
    const float* __restrict__ W2, const float* __restrict__ b2,
    const float* __restrict__ noi, int* __restrict__ cur,
    int* __restrict__ idxo)
{
    __shared__ float hp_l[1024];
    __shared__ float w2_l[64];
    __shared__ int   nv_l[16];
    const int tid = threadIdx.x;
    const int nl = tid >> 4, d = tid & 15;
    const int gi0 = blockIdx.x << 4;
    const int gi = gi0 + nl;
    *(float4*)(hp_l + (tid<<2)) = *(const float4*)(hpre + ((size_t)gi0<<6) + (tid<<2));
    if (tid < 64) w2_l[tid] = W2[tid];
    __syncthreads();
    const int ci  = cur[gi];
    const int nbr = dst[ci*DEG + d];
    float lp = b2[0];
    const float* pj = proj + ((size_t)nbr<<6);
    const float* hh = hp_l + (nl<<6);
#pragma unroll
    for (int h=0; h<64; h+=4){
        float4 p4 = *(const float4*)(pj + h);
        float4 h4 = *(const float4*)(hh + h);
        float4 w4 = *(const float4*)(w2_l + h);
        lp = fmaf(fmaxf(h4.x+p4.x,0.f), w4.x, lp);
        lp = fmaf(fmaxf(h4.y+p4.y,0.f), w4.y, lp);
        lp = fmaf(fmaxf(h4.z+p4.z,0.f), w4.z, lp);
        lp = fmaf(fmaxf(h4.w+p4.w,0.f), w4.w, lp);
    }
    float mx = lp;
#pragma unroll
    for (int off=8; off; off>>=1) mx = fmaxf(mx, __shfl_xor(mx, off, 16));
    float s = expf(lp - mx);
#pragma unroll
    for (int off=8; off; off>>=1) s += __shfl_xor(s, off, 16);
    float p = expf(lp - mx - logf(s)) + noi[((size_t)gi<<4) + d];
    float bv = p; int bi = d;
#pragma unroll
    for (int off=8; off; off>>=1){
        float ov = __shfl_xor(bv, off, 16);
        int   oi = __shfl_xor(bi, off, 16);
        if (ov > bv || (ov == bv && oi < bi)){ bv = ov; bi = oi; }
    }
    int sn = __shfl(nbr, bi, 16);
    if (d == 0){ cur[gi] = sn; idxo[gi] = sn; nv_l[nl] = sn; }
    __syncthreads();
    const int n2 = tid >> 4;
    const int h4i = (tid & 15) << 2;
    const int v = nv_l[n2];
    float4 u  = *(const float4*)(proj + ((size_t)v<<6) + h4i);
    float4 hp = *(const float4*)(hp_l + (n2<<6) + h4i);
    hp.x += u.x; hp.y += u.y; hp.z += u.z; hp.w += u.w;
    *(float4*)(hpre + ((size_t)(gi0+n2)<<6) + h4i) = hp;
}

// ---------------- pack kernels ----------------
__global__ __launch_bounds__(256) void k_pack_x(const float* __restrict__ na,
    unsigned short* __restrict__ Xb)
{
    int i = blockIdx.x*256 + threadIdx.x;   // NND*32 float4 groups
    if (i < NND*32){
        float4 v = *(const float4*)(na + (size_t)i*4);
        unsigned long long pk = (unsigned long long)f2bf(v.x)
            | ((unsigned long long)f2bf(v.y) << 16)
            | ((unsigned long long)f2bf(v.z) << 32)
            | ((unsigned long long)f2bf(v.w) << 48);
        *(unsigned long long*)(Xb + (size_t)i*4) = pk;
    }
}

// BqT[q][k], q in [0,512): j=q>>2, g=q&3; k<128: Wh rows, k>=128: Wx rows.
// g0: W*r, g1: W*z, g2: Whn (x rows 0), g3: Wxn (h rows 0)
__global__ __launch_bounds__(256) void k_pack_bqt(const float* __restrict__ Wx,
    const float* __restrict__ Wh, unsigned short* __restrict__ BqT)
{
    int i = blockIdx.x*256 + threadIdx.x;  // 512*256 = 131072
    int q = i >> 8, k = i & 255;
    int j = q >> 2, g = q & 3;
    float v = 0.f;
    if (k < 128){
        if (g == 0)      v = Wh[k*384 + j];
        else if (g == 1) v = Wh[k*384 + 128 + j];
        else if (g == 2) v = Wh[k*384 + 256 + j];
    } else {
        int kk = k - 128;
        if (g == 0)      v = Wx[kk*384 + j];
        else if (g == 1) v = Wx[kk*384 + 128 + j];
        else if (g == 3) v = Wx[kk*384 + 256 + j];
    }
    BqT[i] = f2bf(v);
}

__global__ __launch_bounds__(256) void k_pack_wot(const float* __restrict__ Wo,
    unsigned short* __restrict__ WoT)
{
    int i = blockIdx.x*256 + threadIdx.x;  // 16384
    int n = i >> 7, k = i & 127;
    WoT[i] = f2bf(Wo[k*128 + n]);
}

// ---------------- fused GRU step: [h | x_gather] @ BqT via MFMA + gate epilogue ----
// grid (391, 4), block 256 (4 waves). BM=128 rows, BN=128 packed cols, K=256 (2 phases).
// LDS A in frag-contiguous layout: [tile(8)][kstep(4)][lane(64)][8] bf16 = 32 KB.
__global__ __launch_bounds__(256,2) void k_gruM(
    const unsigned short* __restrict__ hb_in,
    const unsigned short* __restrict__ Xb,
    const unsigned short* __restrict__ BqT,
    const float* __restrict__ bx, const float* __restrict__ bh,
    const int* __restrict__ xidx,
    unsigned short* __restrict__ hb_out, const int first)
{
    __shared__ unsigned short A_l[16384];
    const int tid = threadIdx.x;
    const int w = tid >> 6, lane = tid & 63;
    const int c = lane & 15, quad = lane >> 4;
    const int row0 = blockIdx.x << 7;
    const int cb = blockIdx.y << 7;
    float4v zero = {0.f, 0.f, 0.f, 0.f};
    float4v acc[2][8];
#pragma unroll
    for (int i=0;i<2;i++)
#pragma unroll
        for (int j=0;j<8;j++) acc[i][j] = zero;

    const int srow = tid >> 1, half = tid & 1;
    int gr = row0 + srow; if (gr >= NND) gr = NND-1;

    for (int ph = first ? 1 : 0; ph < 2; ph++){
        const unsigned short* src = (ph == 0) ? (hb_in + (size_t)gr*128)
                                              : (Xb + (size_t)xidx[gr]*128);
#pragma unroll
        for (int i=0;i<8;i++){
            int c8 = half*8 + i;
            short8v v = *(const short8v*)(src + c8*8);
            int off = (((srow>>4)*4 + (c8>>2))*64 + (c8&3)*16 + (srow&15))*8;
            *(short8v*)(A_l + off) = v;
        }
        __syncthreads();
#pragma unroll
        for (int ks=0; ks<4; ks++){
            short8v a0 = *(const short8v*)(A_l + (((w*2+0)*4 + ks)*64 + lane)*8);
            short8v a1 = *(const short8v*)(A_l + (((w*2+1)*4 + ks)*64 + lane)*8);
            const int kglob = (ph<<7) + (ks<<5) + (quad<<3);
#pragma unroll
            for (int ct=0; ct<8; ct++){
                int q = cb + (ct<<4) + c;
                short8v bf = *(const short8v*)(BqT + ((size_t)q<<8) + kglob);
                acc[0][ct] = __builtin_amdgcn_mfma_f32_16x16x32_bf16(a0, bf, acc[0][ct], 0, 0, 0);
                acc[1][ct] = __builtin_amdgcn_mfma_f32_16x16x32_bf16(a1, bf, acc[1][ct], 0, 0, 0);
            }
        }
        __syncthreads();
    }
    // epilogue: lane's packed col q = cb+ct*16+c, gate g = c&3, j = q>>2.
    // lanes l, l^1, l^2, l^3 hold gates g^{0,1,2,3} for the same j and rows.
    const int myg = c & 3;
#pragma unroll
    for (int ct=0; ct<8; ct++){
        const int j = (cb>>2) + (ct<<2) + (c>>2);
        const float bxr = bx[j],       bhr = bh[j];
        const float bxz = bx[128 + j], bhz = bh[128 + j];
        const float bxn = bx[256 + j], bhn = bh[256 + j];
#pragma unroll
        for (int rt=0; rt<2; rt++){
            float4v a0 = acc[rt][ct];
            float4v g1v, g2v, g3v;
#pragma unroll
            for (int r=0;r<4;r++){
                g1v[r] = __shfl_xor(a0[r], 1);
                g2v[r] = __shfl_xor(a0[r], 2);
                g3v[r] = __shfl_xor(a0[r], 3);
            }
            if (myg == 0){
#pragma unroll
                for (int r=0;r<4;r++){
                    int row = row0 + (w<<5) + (rt<<4) + (quad<<2) + r;
                    if (row < NND){
                        float rr = sigf(a0[r] + bxr + bhr);
                        float zz = sigf(g1v[r] + bxz + bhz);
                        float nn = tanhf(g3v[r] + bxn + rr*(g2v[r] + bhn));
                        float hp = first ? 0.f : bf2f(hb_in[(size_t)row*128 + j]);
                        hb_out[(size_t)row*128 + j] = f2bf((1.f - zz)*nn + zz*hp);
                    }
                }
            }
        }
    }
}

// out(N x 128) = hb(N x 128 bf16) @ Wo + bo, MFMA. grid (391), block 256.
__global__ __launch_bounds__(256,2) void k_outM(
    const unsigned short* __restrict__ hb,
    const unsigned short* __restrict__ WoT,
    const float* __restrict__ bo, float* __restrict__ out)
{
    __shared__ unsigned short A_l[16384];
    const int tid = threadIdx.x;
    const int w = tid >> 6, lane = tid & 63;
    const int c = lane & 15, quad = lane >> 4;
    const int row0 = blockIdx.x << 7;
    float4v zero = {0.f, 0.f, 0.f, 0.f};
    float4v acc[2][8];
#pragma unroll
    for (int i=0;i<2;i++)
#pragma unroll
        for (int j=0;j<8;j++) acc[i][j] = zero;

    const int srow = tid >> 1, half = tid & 1;
    int gr = row0 + srow; if (gr >= NND) gr = NND-1;
    const unsigned short* src = hb + (size_t)gr*128;
#pragma unroll
    for (int i=0;i<8;i++){
        int c8 = half*8 + i;
        short8v v = *(const short8v*)(src + c8*8);
        int off = (((srow>>4)*4 + (c8>>2))*64 + (c8&3)*16 + (srow&15))*8;
        *(short8v*)(A_l + off) = v;
    }
    __syncthreads();
#pragma unroll
    for (int ks=0; ks<4; ks++){
        short8v a0 = *(const short8v*)(A_l + (((w*2+0)*4 + ks)*64 + lane)*8);
        short8v a1 = *(const short8v*)(A_l + (((w*2+1)*4 + ks)*64 + lane)*8);
        const int kglob = (ks<<5) + (quad<<3);
#pragma unroll
        for (int ct=0; ct<8; ct++){
            int q = (ct<<4) + c;
            short8v bf = *(const short8v*)(WoT + ((size_t)q<<7) + kglob);
            acc[0][ct] = __builtin_amdgcn_mfma_f32_16x16x32_bf16(a0, bf, acc[0][ct], 0, 0, 0);
            acc[1][ct] = __builtin_amdgcn_mfma_f32_16x16x32_bf16(a1, bf, acc[1][ct], 0, 0, 0);
        }
    }
#pragma unroll
    for (int ct=0; ct<8; ct++){
        int col = (ct<<4) + c;
        float bb = bo[col];
#pragma unroll
        for (int rt=0; rt<2; rt++){
#pragma unroll
            for (int r=0;r<4;r++){
                int row = row0 + (w<<5) + (rt<<4) + (quad<<2) + r;
                if (row < NND) out[(size_t)row*128 + col] = acc[rt][ct][r] + bb;
            }
        }
    }
}

extern "C" void kernel_launch(void* const* d_in, const int* in_sizes, int n_in,
                              void* d_out, int out_size, void* d_ws, size_t ws_size,
                              hipStream_t stream)
{
    const float* node_attr = (const float*)d_in[0];
    const int*   edge_index= (const int*)  d_in[1];
    // d_in[2] = slices: slices[i,0] == i*DEG by construction -> not needed
    const float* noise = (const float*)d_in[3];
    const float* W1 = (const float*)d_in[4];
    const float* b1 = (const float*)d_in[5];
    const float* W2 = (const float*)d_in[6];
    const float* b2 = (const float*)d_in[7];
    const float* Wx = (const float*)d_in[8];
    const float* Wh = (const float*)d_in[9];
    const float* bx = (const float*)d_in[10];
    const float* bh = (const float*)d_in[11];
    const float* Wo = (const float*)d_in[12];
    const float* bo = (const float*)d_in[13];
    const int* dst = edge_index + (size_t)NND*DEG;
    float* out = (float*)d_out;
    if (ws_size < WS_NEED) return;

    char* ws = (char*)d_ws;
    float* hpre = (float*)(ws + OFF_HPRE);
    float* proj = (float*)(ws + OFF_PROJ);
    unsigned short* Xb  = (unsigned short*)(ws + OFF_XB);
    unsigned short* hbA = (unsigned short*)(ws + OFF_HBA);
    unsigned short* hbB = (unsigned short*)(ws + OFF_HBB);
    int* idxb = (int*)(ws + OFF_IDX);
    int* cur  = (int*)(ws + OFF_CUR);
    unsigned short* BqT = (unsigned short*)(ws + OFF_BQT);
    unsigned short* WoT = (unsigned short*)(ws + OFF_WOT);

    k_iota<<<dim3(196), dim3(256), 0, stream>>>(cur, idxb);
    k_pack_x  <<<dim3(6250), dim3(256), 0, stream>>>(node_attr, Xb);
    k_pack_bqt<<<dim3(512),  dim3(256), 0, stream>>>(Wx, Wh, BqT);
    k_pack_wot<<<dim3(64),   dim3(256), 0, stream>>>(Wo, WoT);

    // walk phase (fp32 exact)
    k_proj<<<dim3(782), dim3(256), 0, stream>>>(node_attr, W1, b1, hpre);
    for (int t = 0; t < 4; t++){
        k_proj<<<dim3(782), dim3(256), 0, stream>>>(node_attr, W1 + (size_t)(1+t)*128*64, nullptr, proj);
        k_walk<<<dim3(3125), dim3(256), 0, stream>>>(hpre, proj, dst, W2, b2,
                 noise + (size_t)t*NND*DEG, cur, idxb + (size_t)(t+1)*NND);
    }
    // GRU: 5 fused MFMA steps (s=0 skips h-phase, hold=0)
    for (int s = 0; s < 5; s++){
        const unsigned short* hi = (s & 1) ? hbA : hbB;
        unsigned short*       ho = (s & 1) ? hbB : hbA;
        k_gruM<<<dim3(391, 4), dim3(256), 0, stream>>>(hi, Xb, BqT, bx, bh,
                 idxb + (size_t)s*NND, ho, s == 0 ? 1 : 0);
    }
    k_outM<<<dim3(391), dim3(256), 0, stream>>>(hbA, WoT, bo, out);
}

// Round 3
// 641.272 us; speedup vs baseline: 2.0577x; 2.0577x over previous
//
#include <hip/hip_runtime.h>
#include <math.h>

#define NND 50000
#define DEG 16

typedef __attribute__((ext_vector_type(8))) short short8v;
typedef __attribute__((ext_vector_type(4))) float float4v;

// ---- workspace layout (bytes) ----
#define OFF_HPRE 0ULL          // N x 64 f32
#define OFF_PROJ 12800000ULL   // N x 64 f32
#define OFF_XB   25600000ULL   // N x 128 bf16
#define OFF_HBA  38400000ULL   // N x 128 bf16
#define OFF_HBB  51200000ULL   // N x 128 bf16
#define OFF_IDX  64000000ULL   // 5*N int
#define OFF_CUR  65000192ULL   // N int
#define OFF_BQT  65200384ULL   // BqF: 4y x 8c x 8ct x 64 x 8 bf16 = 256 KB
#define OFF_WOT  65462528ULL   // WoF: 4c x 8ct x 64 x 8 bf16 = 32 KB
#define WS_NEED  65495296ULL

__device__ __forceinline__ float sigf(float x){ return 1.0f/(1.0f + expf(-x)); }
__device__ __forceinline__ unsigned short f2bf(float f){
    unsigned int u = __float_as_uint(f);
    u += 0x7FFFu + ((u >> 16) & 1u);
    return (unsigned short)(u >> 16);
}
__device__ __forceinline__ float bf2f(unsigned short h){
    return __uint_as_float(((unsigned int)h) << 16);
}

__global__ __launch_bounds__(256) void k_iota(int* __restrict__ cur, int* __restrict__ idx0){
    int i = blockIdx.x*256 + threadIdx.x;
    if (i < NND){ cur[i] = i; idx0[i] = i; }
}

// ---------------- walk phase (fp32, untouched: argmax determinism) ----------------
__global__ __launch_bounds__(256) void k_proj(const float* __restrict__ A,
    const float* __restrict__ B, const float* __restrict__ bias,
    float* __restrict__ out)
{
    __shared__ float Al[64][33];
    __shared__ float Bl[32][68];
    const int tid = threadIdx.x;
    const int row0 = blockIdx.x << 6;
    const int row_t = tid >> 4, col_t = tid & 15;
    float4 acc[4];
#pragma unroll
    for (int i=0;i<4;i++) acc[i] = make_float4(0.f,0.f,0.f,0.f);
    for (int k0 = 0; k0 < 128; k0 += 32){
#pragma unroll
        for (int r=0;r<2;r++){
            int am = (tid>>3) + (r<<5);
            int ak = (tid&7) << 2;
            int gr = row0 + am; if (gr >= NND) gr = NND-1;
            float4 v = *(const float4*)(A + (size_t)gr*128 + k0 + ak);
            Al[am][ak] = v.x; Al[am][ak+1] = v.y; Al[am][ak+2] = v.z; Al[am][ak+3] = v.w;
        }
#pragma unroll
        for (int r=0;r<2;r++){
            int p = (r<<8) + tid;
            int bk = p >> 4, bc = (p & 15) << 2;
            *(float4*)(&Bl[bk][bc]) = *(const float4*)(B + (size_t)(k0+bk)*64 + bc);
        }
        __syncthreads();
#pragma unroll 8
        for (int k=0;k<32;k++){
            float4 b = *(const float4*)(&Bl[k][col_t<<2]);
#pragma unroll
            for (int i=0;i<4;i++){
                float a = Al[(row_t<<2)+i][k];
                acc[i].x = fmaf(a, b.x, acc[i].x);
                acc[i].y = fmaf(a, b.y, acc[i].y);
                acc[i].z = fmaf(a, b.z, acc[i].z);
                acc[i].w = fmaf(a, b.w, acc[i].w);
            }
        }
        __syncthreads();
    }
    float4 bb = make_float4(0.f,0.f,0.f,0.f);
    if (bias) bb = *(const float4*)(bias + (col_t<<2));
#pragma unroll
    for (int i=0;i<4;i++){
        int gr = row0 + (row_t<<2) + i;
        if (gr < NND){
            float4 o = make_float4(acc[i].x+bb.x, acc[i].y+bb.y, acc[i].z+bb.z, acc[i].w+bb.w);
            *(float4*)(out + (size_t)gr*64 + (col_t<<2)) = o;
        }
    }
}

__global__ __launch_bounds__(256) void k_walk(float* __restrict__ hpre,
    const float* __restrict__ proj, const int* __restrict__ dst,
    const float* __restrict__ W2, const float* __restrict__ b2,
    const float* __restrict__ noi, int* __restrict__ cur,
    int* __restrict__ idxo)
{
    __shared__ float hp_l[1024];
    __shared__ float w2_l[64];
    __shared__ int   nv_l[16];
    const int tid = threadIdx.x;
    const int nl = tid >> 4, d = tid & 15;
    const int gi0 = blockIdx.x << 4;
    const int gi = gi0 + nl;
    *(float4*)(hp_l + (tid<<2)) = *(const float4*)(hpre + ((size_t)gi0<<6) + (tid<<2));
    if (tid < 64) w2_l[tid] = W2[tid];
    __syncthreads();
    const int ci  = cur[gi];
    const int nbr = dst[ci*DEG + d];
    float lp = b2[0];
    const float* pj = proj + ((size_t)nbr<<6);
    const float* hh = hp_l + (nl<<6);
#pragma unroll
    for (int h=0; h<64; h+=4){
        float4 p4 = *(const float4*)(pj + h);
        float4 h4 = *(const float4*)(hh + h);
        float4 w4 = *(const float4*)(w2_l + h);
        lp = fmaf(fmaxf(h4.x+p4.x,0.f), w4.x, lp);
        lp = fmaf(fmaxf(h4.y+p4.y,0.f), w4.y, lp);
        lp = fmaf(fmaxf(h4.z+p4.z,0.f), w4.z, lp);
        lp = fmaf(fmaxf(h4.w+p4.w,0.f), w4.w, lp);
    }
    float mx = lp;
#pragma unroll
    for (int off=8; off; off>>=1) mx = fmaxf(mx, __shfl_xor(mx, off, 16));
    float s = expf(lp - mx);
#pragma unroll
    for (int off=8; off; off>>=1) s += __shfl_xor(s, off, 16);
    float p = expf(lp - mx - logf(s)) + noi[((size_t)gi<<4) + d];
    float bv = p; int bi = d;
#pragma unroll
    for (int off=8; off; off>>=1){
        float ov = __shfl_xor(bv, off, 16);
        int   oi = __shfl_xor(bi, off, 16);
        if (ov > bv || (ov == bv && oi < bi)){ bv = ov; bi = oi; }
    }
    int sn = __shfl(nbr, bi, 16);
    if (d == 0){ cur[gi] = sn; idxo[gi] = sn; nv_l[nl] = sn; }
    __syncthreads();
    const int n2 = tid >> 4;
    const int h4i = (tid & 15) << 2;
    const int v = nv_l[n2];
    float4 u  = *(const float4*)(proj + ((size_t)v<<6) + h4i);
    float4 hp = *(const float4*)(hp_l + (n2<<6) + h4i);
    hp.x += u.x; hp.y += u.y; hp.z += u.z; hp.w += u.w;
    *(float4*)(hpre + ((size_t)(gi0+n2)<<6) + h4i) = hp;
}

// ---------------- pack kernels ----------------
__global__ __launch_bounds__(256) void k_pack_x(const float* __restrict__ na,
    unsigned short* __restrict__ Xb)
{
    int i = blockIdx.x*256 + threadIdx.x;
    if (i < NND*32){
        float4 v = *(const float4*)(na + (size_t)i*4);
        unsigned long long pk = (unsigned long long)f2bf(v.x)
            | ((unsigned long long)f2bf(v.y) << 16)
            | ((unsigned long long)f2bf(v.z) << 32)
            | ((unsigned long long)f2bf(v.w) << 48);
        *(unsigned long long*)(Xb + (size_t)i*4) = pk;
    }
}

// BqF[y][c][ct][lane][8]: gate-blocked, MFMA-16x16x32 B-frag order.
// ct = gate*2 + jh; col j = y*32 + jh*16 + (lane&15); k = c*32 + (lane>>4)*8 + jj.
// k<128: Wh rows (gate 3 -> 0); k>=128: Wx rows (gate 2 -> 0).
__global__ __launch_bounds__(256) void k_pack_bqf(const float* __restrict__ Wx,
    const float* __restrict__ Wh, unsigned short* __restrict__ BqF)
{
    int i = blockIdx.x*256 + threadIdx.x;  // 131072
    int jj = i & 7, lane = (i>>3)&63, ct = (i>>9)&7, c = (i>>12)&7, y = i>>15;
    int g = ct>>1, jh = ct&1, mm = lane&15, quad = lane>>4;
    int jg = (y<<5) + (jh<<4) + mm;
    int k = (c<<5) + (quad<<3) + jj;
    float v = 0.f;
    if (k < 128){
        if (g < 3) v = Wh[k*384 + g*128 + jg];
    } else {
        int kk = k - 128;
        if (g == 0)      v = Wx[kk*384 + jg];
        else if (g == 1) v = Wx[kk*384 + 128 + jg];
        else if (g == 3) v = Wx[kk*384 + 256 + jg];
    }
    BqF[i] = f2bf(v);
}

// WoF[c][ct][lane][8]: n = ct*16 + (lane&15), k = c*32 + (lane>>4)*8 + jj
__global__ __launch_bounds__(256) void k_pack_wof(const float* __restrict__ Wo,
    unsigned short* __restrict__ WoF)
{
    int i = blockIdx.x*256 + threadIdx.x;  // 16384
    int jj = i & 7, lane = (i>>3)&63, ct = (i>>9)&7, c = i>>12;
    int n = (ct<<4) + (lane&15);
    int k = (c<<5) + ((lane>>4)<<3) + jj;
    WoF[i] = f2bf(Wo[k*128 + n]);
}

// ---------------- GRU step v3 ----------------
// grid (391, 4), block 256. BM=128 rows, 4 waves x 32 rows (rt=2 of 16).
// BN=128 packed cols = 4 gates x 32 j (gates in ct => in-lane epilogue).
// K=256 in 8 chunks of 32; A chunk staged in frag-contiguous LDS (8 KB);
// B frags direct from BqF (coalesced 1 KB wave-reads, L2-resident).
__global__ __launch_bounds__(256,2) void k_gruM(
    const unsigned short* __restrict__ hb_in,
    const unsigned short* __restrict__ Xb,
    const unsigned short* __restrict__ BqF,
    const float* __restrict__ bx, const float* __restrict__ bh,
    const int* __restrict__ xidx,
    unsigned short* __restrict__ hb_out, const int first)
{
    __shared__ unsigned short A_l[4096];  // 512 x 16B frag units
    const int tid = threadIdx.x;
    const int w = tid >> 6, lane = tid & 63;
    const int m = lane & 15, quad = lane >> 4;
    const int row0 = blockIdx.x << 7;
    const int y = blockIdx.y;
    float4v zero = {0.f,0.f,0.f,0.f};
    float4v acc[2][8];
#pragma unroll
    for (int i=0;i<2;i++)
#pragma unroll
        for (int jx=0;jx<8;jx++) acc[i][jx] = zero;

    const int r  = tid & 127, kq = tid >> 7;
    int gr = row0 + r; if (gr >= NND) gr = NND-1;
    const int xr = xidx[gr];
    const unsigned short* hrow = hb_in + (size_t)gr*128;
    const unsigned short* xrow = Xb + (size_t)xr*128;
    // unit(r,q) = (r>>4)*64 + q*16 + (r&15); this thread writes q=2kq, 2kq+1
    unsigned short* wp = A_l + (((r>>4)<<6) + (kq<<5) + (r&15))*8;

    const int c0 = first ? 4 : 0;
    for (int c = c0; c < 8; c++){
        const unsigned short* src = (c < 4) ? (hrow + (c<<5) + (kq<<4))
                                            : (xrow + ((c-4)<<5) + (kq<<4));
        short8v v0 = *(const short8v*)(src);
        short8v v1 = *(const short8v*)(src + 8);
        // B frags for this chunk: issue early, coalesced, overlap with staging
        const unsigned short* bp = BqF + ((((size_t)y*8 + c)*8*64) + lane)*8;
        __syncthreads();
        *(short8v*)(wp)       = v0;
        *(short8v*)(wp + 128) = v1;
        __syncthreads();
        short8v a0 = *(const short8v*)(A_l + ((w<<1)+0)*512 + lane*8);
        short8v a1 = *(const short8v*)(A_l + ((w<<1)+1)*512 + lane*8);
#pragma unroll
        for (int ct=0; ct<8; ct++){
            short8v bf = *(const short8v*)(bp + (ct<<9));
            acc[0][ct] = __builtin_amdgcn_mfma_f32_16x16x32_bf16(a0, bf, acc[0][ct], 0,0,0);
            acc[1][ct] = __builtin_amdgcn_mfma_f32_16x16x32_bf16(a1, bf, acc[1][ct], 0,0,0);
        }
    }
    // in-lane epilogue: gates r,z,hn,xn live in acc[rt][g*2+jh], same lane
#pragma unroll
    for (int jh=0; jh<2; jh++){
        const int j = (y<<5) + (jh<<4) + m;
        const float brr = bx[j]       + bh[j];
        const float bzz = bx[128 + j] + bh[128 + j];
        const float bxn = bx[256 + j];
        const float bhn = bh[256 + j];
#pragma unroll
        for (int rt=0; rt<2; rt++){
#pragma unroll
            for (int r4=0; r4<4; r4++){
                int row = row0 + (w<<5) + (rt<<4) + (quad<<2) + r4;
                if (row < NND){
                    float rg = sigf(acc[rt][jh][r4] + brr);
                    float zg = sigf(acc[rt][2+jh][r4] + bzz);
                    float ng = tanhf(acc[rt][6+jh][r4] + bxn + rg*(acc[rt][4+jh][r4] + bhn));
                    float hp = first ? 0.f : bf2f(hb_in[(size_t)row*128 + j]);
                    hb_out[(size_t)row*128 + j] = f2bf((1.f - zg)*ng + zg*hp);
                }
            }
        }
    }
}

// out = hb @ Wo + bo, same v3 structure, K=128 (4 chunks), f32 out
__global__ __launch_bounds__(256,2) void k_outM(
    const unsigned short* __restrict__ hb,
    const unsigned short* __restrict__ WoF,
    const float* __restrict__ bo, float* __restrict__ out)
{
    __shared__ unsigned short A_l[4096];
    const int tid = threadIdx.x;
    const int w = tid >> 6, lane = tid & 63;
    const int m = lane & 15, quad = lane >> 4;
    const int row0 = blockIdx.x << 7;
    float4v zero = {0.f,0.f,0.f,0.f};
    float4v acc[2][8];
#pragma unroll
    for (int i=0;i<2;i++)
#pragma unroll
        for (int jx=0;jx<8;jx++) acc[i][jx] = zero;

    const int r  = tid & 127, kq = tid >> 7;
    int gr = row0 + r; if (gr >= NND) gr = NND-1;
    const unsigned short* hrow = hb + (size_t)gr*128;
    unsigned short* wp = A_l + (((r>>4)<<6) + (kq<<5) + (r&15))*8;

    for (int c = 0; c < 4; c++){
        const unsigned short* src = hrow + (c<<5) + (kq<<4);
        short8v v0 = *(const short8v*)(src);
        short8v v1 = *(const short8v*)(src + 8);
        const unsigned short* bp = WoF + (((size_t)c*8*64) + lane)*8;
        __syncthreads();
        *(short8v*)(wp)       = v0;
        *(short8v*)(wp + 128) = v1;
        __syncthreads();
        short8v a0 = *(const short8v*)(A_l + ((w<<1)+0)*512 + lane*8);
        short8v a1 = *(const short8v*)(A_l + ((w<<1)+1)*512 + lane*8);
#pragma unroll
        for (int ct=0; ct<8; ct++){
            short8v bf = *(const short8v*)(bp + (ct<<9));
            acc[0][ct] = __builtin_amdgcn_mfma_f32_16x16x32_bf16(a0, bf, acc[0][ct], 0,0,0);
            acc[1][ct] = __builtin_amdgcn_mfma_f32_16x16x32_bf16(a1, bf, acc[1][ct], 0,0,0);
        }
    }
#pragma unroll
    for (int ct=0; ct<8; ct++){
        int col = (ct<<4) + m;
        float bb = bo[col];
#pragma unroll
        for (int rt=0; rt<2; rt++){
#pragma unroll
            for (int r4=0; r4<4; r4++){
                int row = row0 + (w<<5) + (rt<<4) + (quad<<2) + r4;
                if (row < NND) out[(size_t)row*128 + col] = acc[rt][ct][r4] + bb;
            }
        }
    }
}

extern "C" void kernel_launch(void* const* d_in, const int* in_sizes, int n_in,
                              void* d_out, int out_size, void* d_ws, size_t ws_size,
                              hipStream_t stream)
{
    const float* node_attr = (const float*)d_in[0];
    const int*   edge_index= (const int*)  d_in[1];
    const float* noise = (const float*)d_in[3];
    const float* W1 = (const float*)d_in[4];
    const float* b1 = (const float*)d_in[5];
    const float* W2 = (const float*)d_in[6];
    const float* b2 = (const float*)d_in[7];
    const float* Wx = (const float*)d_in[8];
    const float* Wh = (const float*)d_in[9];
    const float* bx = (const float*)d_in[10];
    const float* bh = (const float*)d_in[11];
    const float* Wo = (const float*)d_in[12];
    const float* bo = (const float*)d_in[13];
    const int* dst = edge_index + (size_t)NND*DEG;
    float* out = (float*)d_out;
    if (ws_size < WS_NEED) return;

    char* ws = (char*)d_ws;
    float* hpre = (float*)(ws + OFF_HPRE);
    float* proj = (float*)(ws + OFF_PROJ);
    unsigned short* Xb  = (unsigned short*)(ws + OFF_XB);
    unsigned short* hbA = (unsigned short*)(ws + OFF_HBA);
    unsigned short* hbB = (unsigned short*)(ws + OFF_HBB);
    int* idxb = (int*)(ws + OFF_IDX);
    int* cur  = (int*)(ws + OFF_CUR);
    unsigned short* BqF = (unsigned short*)(ws + OFF_BQT);
    unsigned short* WoF = (unsigned short*)(ws + OFF_WOT);

    k_iota<<<dim3(196), dim3(256), 0, stream>>>(cur, idxb);
    k_pack_x  <<<dim3(6250), dim3(256), 0, stream>>>(node_attr, Xb);
    k_pack_bqf<<<dim3(512),  dim3(256), 0, stream>>>(Wx, Wh, BqF);
    k_pack_wof<<<dim3(64),   dim3(256), 0, stream>>>(Wo, WoF);

    // walk phase (fp32 exact)
    k_proj<<<dim3(782), dim3(256), 0, stream>>>(node_attr, W1, b1, hpre);
    for (int t = 0; t < 4; t++){
        k_proj<<<dim3(782), dim3(256), 0, stream>>>(node_attr, W1 + (size_t)(1+t)*128*64, nullptr, proj);
        k_walk<<<dim3(3125), dim3(256), 0, stream>>>(hpre, proj, dst, W2, b2,
                 noise + (size_t)t*NND*DEG, cur, idxb + (size_t)(t+1)*NND);
    }
    // GRU: 5 fused MFMA steps
    for (int s = 0; s < 5; s++){
        const unsigned short* hi = (s & 1) ? hbA : hbB;
        unsigned short*       ho = (s & 1) ? hbB : hbA;
        k_gruM<<<dim3(391, 4), dim3(256), 0, stream>>>(hi, Xb, BqF, bx, bh,
                 idxb + (size_t)s*NND, ho, s == 0 ? 1 : 0);
    }
    k_outM<<<dim3(391), dim3(256), 0, stream>>>(hbA, WoF, bo, out);
}